// Round 1
// baseline (375.568 us; speedup 1.0000x reference)
//
#include <hip/hip_runtime.h>

#define NN 50000
#define DD 128
#define EE 800000
#define SLOTS 64          // max degree cap (Poisson(16): P(deg>=65) ~ 1e-20/node)
#define CSTRIDE 16        // ints per counter -> one counter per 64B line
#define NSHARD 8          // XCDs; blockIdx % 8 ~ XCD round-robin (perf heuristic only)
#define SHARD_NODES (NN / NSHARD)   // 6250

// merged prep+bucket block ranges (bucket first: it's the long pole)
#define BKT_BLKS  6256    // 782 chunks x 8 shards
#define CVT_BLKS  6250    // NN*DD/4 float4s / 256
#define WCAT_BLKS 384
#define ZR_BLKS   1

// zero pass: cntpad (200000 uint4) + eidx sentinel fill (400000 uint4)
#define ZCNT_U4   (NN * CSTRIDE / 4)
#define ZEIDX_U4  (NN * SLOTS / 8)
#define ZR_GRID   ((ZCNT_U4 + ZEIDX_U4 + 255) / 256)

typedef short bf16x8 __attribute__((ext_vector_type(8)));   // 8 bf16 = 4 VGPRs
typedef float f32x4  __attribute__((ext_vector_type(4)));

// ---- bf16 helpers (RNE) ----
__device__ __forceinline__ unsigned short f2bf(float f) {
    union { float f; unsigned u; } c; c.f = f;
    unsigned r = c.u + 0x7fffu + ((c.u >> 16) & 1u);
    return (unsigned short)(r >> 16);
}
__device__ __forceinline__ float bflo(unsigned p) { union { unsigned u; float f; } c; c.u = p << 16; return c.f; }
__device__ __forceinline__ float bfhi(unsigned p) { union { unsigned u; float f; } c; c.u = p & 0xffff0000u; return c.f; }
__device__ __forceinline__ unsigned packbf(float a, float b) { return (unsigned)f2bf(a) | ((unsigned)f2bf(b) << 16); }

// ---------------- cnt zero + eidx sentinel fill (must precede bucket atomics) ----------------
// eidx prefilled with NN (0xC350) so slots >= deg point at the zero sentinel row: the gather
// then needs NO cap-masking and row addresses don't depend on the deg load.
__global__ __launch_bounds__(256) void zero_kernel(int* __restrict__ cntpad, unsigned short* __restrict__ eidx) {
    int i = blockIdx.x * 256 + threadIdx.x;     // uint4 index
    if (i < ZCNT_U4) {
        ((uint4*)cntpad)[i] = make_uint4(0, 0, 0, 0);
    } else {
        int j = i - ZCNT_U4;
        if (j < ZEIDX_U4) ((uint4*)eidx)[j] = make_uint4(0xC350C350u, 0xC350C350u, 0xC350C350u, 0xC350C350u);
    }
}

// ---------------- merged prep + padded-slot CSR build (independent parts, one dispatch) ----
// R11 evidence: bucket (~40us) + prep (~25us) merged costs only ~45us (overlapped).
__global__ __launch_bounds__(256) void prepbucket_kernel(const int* __restrict__ src, const int* __restrict__ dst,
                                                         const float* __restrict__ x,
                                                         const float* __restrict__ W1l, const float* __restrict__ W1r,
                                                         const float* __restrict__ W2l, const float* __restrict__ W2r,
                                                         const float* __restrict__ W3l, const float* __restrict__ W3r,
                                                         int* __restrict__ cntpad, unsigned short* __restrict__ eidx,
                                                         unsigned short* __restrict__ xb,
                                                         unsigned short* __restrict__ Bw,
                                                         unsigned short* __restrict__ h1b,
                                                         unsigned short* __restrict__ h2b) {
    const int b = blockIdx.x;
    const int t = threadIdx.x;
    if (b < BKT_BLKS) {
        const int shard = b & (NSHARD - 1);
        const int chunk = b >> 3;
        const int lo = shard * SHARD_NODES;
        const int hi = lo + SHARD_NODES;
        int i = (chunk * 256 + t) * 4;
        if (i + 3 < EE) {
            int4 dv = *(const int4*)(dst + i);
            int4 sv = *(const int4*)(src + i);
            if (dv.x >= lo && dv.x < hi) { int p = atomicAdd(&cntpad[dv.x * CSTRIDE], 1); if (p < SLOTS) eidx[dv.x * SLOTS + p] = (unsigned short)sv.x; }
            if (dv.y >= lo && dv.y < hi) { int p = atomicAdd(&cntpad[dv.y * CSTRIDE], 1); if (p < SLOTS) eidx[dv.y * SLOTS + p] = (unsigned short)sv.y; }
            if (dv.z >= lo && dv.z < hi) { int p = atomicAdd(&cntpad[dv.z * CSTRIDE], 1); if (p < SLOTS) eidx[dv.z * SLOTS + p] = (unsigned short)sv.z; }
            if (dv.w >= lo && dv.w < hi) { int p = atomicAdd(&cntpad[dv.w * CSTRIDE], 1); if (p < SLOTS) eidx[dv.w * SLOTS + p] = (unsigned short)sv.w; }
        } else {
            for (int e = i; e < EE; ++e) {
                int d = dst[e];
                if (d >= lo && d < hi) {
                    int p = atomicAdd(&cntpad[d * CSTRIDE], 1);
                    if (p < SLOTS) eidx[d * SLOTS + p] = (unsigned short)src[e];
                }
            }
        }
    } else if (b < BKT_BLKS + CVT_BLKS) {
        int i = (b - BKT_BLKS) * 256 + t;         // float4 index, exactly NN*DD/4
        float4 v = ((const float4*)x)[i];
        uint2 o;
        o.x = packbf(v.x, v.y);
        o.y = packbf(v.z, v.w);
        ((uint2*)xb)[i] = o;
    } else if (b < BKT_BLKS + CVT_BLKS + WCAT_BLKS) {
        int gid = (b - BKT_BLKS - CVT_BLKS) * 256 + t;   // 0..98303
        int layer = gid >> 15;
        int rem = gid & 32767;
        int c = rem >> 8;
        int k = rem & 255;
        const float* Wl = (layer == 0) ? W1l : (layer == 1) ? W2l : W3l;
        const float* Wr = (layer == 0) ? W1r : (layer == 1) ? W2r : W3r;
        float v = (k < 128) ? Wl[(size_t)c * DD + k] : Wr[(size_t)c * DD + (k - 128)];
        Bw[gid] = f2bf(v);
    } else {
        // zero sentinel row NN of xb/h1b/h2b: 3 rows x 256B = 48 uint4
        if (t < 48) {
            unsigned short* base = (t < 16) ? xb : (t < 32) ? h1b : h2b;
            ((uint4*)(base + (size_t)NN * DD))[t & 15] = make_uint4(0, 0, 0, 0);
        }
    }
}

// ---------------- fused layer: gather 16 nodes -> LDS, then MFMA dual-GEMM ----------------
// R13 theory: the old Phase A (4 nodes SERIAL per wave + 2-stage shfl-xor tree reduce) was
// latency-bound: VALUBusy 29%, MfmaUtil 2%, HBM 25% -> nothing saturated, per-wave stall ~94%.
// New Phase A: quarter-per-node. lane=(sub,q): each 16-lane quarter owns one node; lane q
// privately accumulates channels q*8..q*8+7 -> NO cross-lane reduce. Per round the wave loads
// 4 rows (one per quarter) x 16 lanes x 16B -- same coalescing as before, but all 4 nodes
// advance concurrently, and rounds are 2-deep software-pipelined (sets A/B, 8 uint4 in
// flight = 32 VGPR; total ~60, keeps __launch_bounds__(256,8) -> 32 waves/CU).
// eidx slots >= deg are sentinel (NN = zero row), so no masking and addresses don't wait on deg.
// Bounds checks dropped: NN = 3125*16 exactly, grid covers all rows.
template <int RELU, int WRITE_F32>
__global__ __launch_bounds__(256, 8) void layer_kernel(const unsigned short* __restrict__ hb,
                                                       const unsigned short* __restrict__ eidx,
                                                       const int* __restrict__ cntpad,
                                                       const unsigned short* __restrict__ Bw,
                                                       const float* __restrict__ bias,
                                                       float* __restrict__ outf,
                                                       unsigned short* __restrict__ outb, int n) {
    (void)n;
    __shared__ __align__(16) unsigned short sA[16][136];
    const int tid  = threadIdx.x;
    const int w    = tid >> 6;          // wave 0..3
    const int lane = tid & 63;
    const int row0 = blockIdx.x * 16;
    const int sub  = lane >> 4;         // quarter 0..3 -> node within wave
    const int q    = lane & 15;         // 16B slot within the 256B row

    // ---- Phase A: 4 nodes per wave, one per quarter ----
    const int node = row0 + (w << 2) + sub;
    const int deg  = cntpad[node * CSTRIDE];
    // lane's 4 slot indices (slots q*4..q*4+3 of its node); sentinel-padded past deg
    uint2 mi = *(const uint2*)(eidx + (size_t)node * SLOTS + q * 4);

    const int cap = deg < SLOTS ? deg : SLOTS;
    int cmax = cap;
    cmax = max(cmax, __shfl_xor(cmax, 16));
    cmax = max(cmax, __shfl_xor(cmax, 32));
    const int rounds = (cmax + 3) >> 2;     // wave-uniform loop bound (shuffles inside)

    float a0 = 0.f, a1 = 0.f, a2 = 0.f, a3 = 0.f, a4 = 0.f, a5 = 0.f, a6 = 0.f, a7 = 0.f;
    uint4 A0, A1, A2, A3, B0, B1, B2, B3;

    auto issue = [&](int r, uint4& v0, uint4& v1, uint4& v2, uint4& v3) {
        const int sl = (sub << 4) | r;                       // source lane holding slots 4r..4r+3
        unsigned p0 = (unsigned)__shfl((int)mi.x, sl);
        unsigned p1 = (unsigned)__shfl((int)mi.y, sl);
        v0 = ((const uint4*)(hb + (size_t)(p0 & 0xffffu) * DD))[q];
        v1 = ((const uint4*)(hb + (size_t)(p0 >> 16)     * DD))[q];
        v2 = ((const uint4*)(hb + (size_t)(p1 & 0xffffu) * DD))[q];
        v3 = ((const uint4*)(hb + (size_t)(p1 >> 16)     * DD))[q];
    };
    auto accum = [&](const uint4& v0, const uint4& v1, const uint4& v2, const uint4& v3) {
        a0 += (bflo(v0.x) + bflo(v1.x)) + (bflo(v2.x) + bflo(v3.x));
        a1 += (bfhi(v0.x) + bfhi(v1.x)) + (bfhi(v2.x) + bfhi(v3.x));
        a2 += (bflo(v0.y) + bflo(v1.y)) + (bflo(v2.y) + bflo(v3.y));
        a3 += (bfhi(v0.y) + bfhi(v1.y)) + (bfhi(v2.y) + bfhi(v3.y));
        a4 += (bflo(v0.z) + bflo(v1.z)) + (bflo(v2.z) + bflo(v3.z));
        a5 += (bfhi(v0.z) + bfhi(v1.z)) + (bfhi(v2.z) + bfhi(v3.z));
        a6 += (bflo(v0.w) + bflo(v1.w)) + (bflo(v2.w) + bflo(v3.w));
        a7 += (bfhi(v0.w) + bfhi(v1.w)) + (bfhi(v2.w) + bfhi(v3.w));
    };

    if (rounds > 0) {
        issue(0, A0, A1, A2, A3);
        if (rounds > 1) issue(1, B0, B1, B2, B3);
        int r = 0;
        while (true) {
            accum(A0, A1, A2, A3);
            if (r + 2 < rounds) issue(r + 2, A0, A1, A2, A3);
            if (++r >= rounds) break;
            accum(B0, B1, B2, B3);
            if (r + 2 < rounds) issue(r + 2, B0, B1, B2, B3);
            if (++r >= rounds) break;
        }
    }

    {
        const float inv = (deg > 0) ? (1.0f / (float)deg) : 0.f;
        uint4 o;
        o.x = packbf(a0 * inv, a1 * inv);
        o.y = packbf(a2 * inv, a3 * inv);
        o.z = packbf(a4 * inv, a5 * inv);
        o.w = packbf(a6 * inv, a7 * inv);
        *(uint4*)&sA[(w << 2) | sub][q * 8] = o;
    }
    __syncthreads();

    // ---- Phase B: MFMA dual-GEMM. All waves share the 16 rows; wave w owns 32 cols ----
    const int m    = lane & 15;
    const int quad = lane >> 4;
    const int arow = row0 + m;

    f32x4 acc[2];
    acc[0] = (f32x4){0.f, 0.f, 0.f, 0.f};
    acc[1] = (f32x4){0.f, 0.f, 0.f, 0.f};

    const unsigned short* aptr = hb + (size_t)arow * DD + quad * 8;
#pragma unroll
    for (int ph = 0; ph < 2; ++ph) {
#pragma unroll
        for (int ks = 0; ks < 4; ++ks) {
            bf16x8 af;
            if (ph == 0) {
                af = *(const bf16x8*)&sA[m][ks * 32 + quad * 8];
            } else {
                af = *(const bf16x8*)(aptr + ks * 32);
            }
            const int koff = ph * 128 + ks * 32 + quad * 8;
#pragma unroll
            for (int ct = 0; ct < 2; ++ct) {
                const int c = w * 32 + ct * 16 + m;
                bf16x8 bfv = *(const bf16x8*)(Bw + (size_t)c * 256 + koff);
                acc[ct] = __builtin_amdgcn_mfma_f32_16x16x32_bf16(af, bfv, acc[ct], 0, 0, 0);
            }
        }
    }

#pragma unroll
    for (int ct = 0; ct < 2; ++ct) {
        const int gcol = w * 32 + ct * 16 + m;
        const float bv = bias[gcol];
#pragma unroll
        for (int r = 0; r < 4; ++r) {
            const int grow = row0 + quad * 4 + r;
            float v = acc[ct][r] + bv;
            if (RELU) v = fmaxf(v, 0.f);
            if (WRITE_F32) outf[(size_t)grow * DD + gcol] = v;
            else           outb[(size_t)grow * DD + gcol] = f2bf(v);
        }
    }
}

extern "C" void kernel_launch(void* const* d_in, const int* in_sizes, int n_in,
                              void* d_out, int out_size, void* d_ws, size_t ws_size,
                              hipStream_t stream) {
    const float* x    = (const float*)d_in[0];
    const int*   edge = (const int*)d_in[1];     // [2, E] int32
    const int*   srcp = edge;
    const int*   dstp = edge + EE;
    const float* W1l = (const float*)d_in[2];
    const float* b1  = (const float*)d_in[3];
    const float* W1r = (const float*)d_in[4];
    const float* W2l = (const float*)d_in[5];
    const float* b2  = (const float*)d_in[6];
    const float* W2r = (const float*)d_in[7];
    const float* W3l = (const float*)d_in[8];
    const float* b3  = (const float*)d_in[9];
    const float* W3r = (const float*)d_in[10];
    float* out = (float*)d_out;

    char* ws = (char*)d_ws;
    size_t off = 0;
    auto alloc = [&](size_t bytes) { void* p = ws + off; off += (bytes + 255) & ~(size_t)255; return p; };
    unsigned short* eidx   = (unsigned short*)alloc((size_t)NN * SLOTS * 2);      // 6.4 MB padded slots
    int*            cntpad = (int*)           alloc((size_t)NN * CSTRIDE * 4);    // 3.2 MB line-strided counters
    unsigned short* Bw     = (unsigned short*)alloc((size_t)3 * DD * 256 * 2);
    unsigned short* xb     = (unsigned short*)alloc((size_t)(NN + 1) * DD * 2);   // +1 zero row (sentinel NN)
    unsigned short* h1b    = (unsigned short*)alloc((size_t)(NN + 1) * DD * 2);
    unsigned short* h2b    = (unsigned short*)alloc((size_t)(NN + 1) * DD * 2);

    zero_kernel<<<ZR_GRID, 256, 0, stream>>>(cntpad, eidx);

    const int pb_grid = BKT_BLKS + CVT_BLKS + WCAT_BLKS + ZR_BLKS;
    prepbucket_kernel<<<pb_grid, 256, 0, stream>>>(srcp, dstp, x, W1l, W1r, W2l, W2r, W3l, W3r,
                                                   cntpad, eidx, xb, Bw, h1b, h2b);

    const int layer_grid = (NN + 15) / 16;     // 3125

    // layer 1: xb -> h1b (ReLU)
    layer_kernel<1, 0><<<layer_grid, 256, 0, stream>>>(xb, eidx, cntpad, Bw, b1, nullptr, h1b, NN);
    // layer 2: h1b -> h2b (ReLU)
    layer_kernel<1, 0><<<layer_grid, 256, 0, stream>>>(h1b, eidx, cntpad, Bw + 32768, b2, nullptr, h2b, NN);
    // layer 3: h2b -> out fp32 (no ReLU)
    layer_kernel<0, 1><<<layer_grid, 256, 0, stream>>>(h2b, eidx, cntpad, Bw + 65536, b3, out, nullptr, NN);
}

// Round 2
// 282.732 us; speedup vs baseline: 1.3284x; 1.3284x over previous
//
#include <hip/hip_runtime.h>

#define NN 50000
#define DD 128
#define EE 800000
#define SLOTS 64          // max degree cap (Poisson(16): P(deg>=65) ~ 1e-20/node)
#define CSTRIDE 16        // ints per counter -> one counter per 64B line
#define NSHARD 8          // XCDs; blockIdx % 8 ~ XCD round-robin (perf heuristic only)
#define SHARD_NODES (NN / NSHARD)   // 6250

// merged prep+bucket block ranges (bucket first: it's the long pole)
#define BKT_BLKS  6256    // 782 chunks x 8 shards
#define CVT_BLKS  6250    // NN*DD/4 float4s / 256
#define WCAT_BLKS 384
#define ZR_BLKS   1

// zero pass: cntpad (200000 uint4) + eidx sentinel fill (400000 uint4)
#define ZCNT_U4   (NN * CSTRIDE / 4)
#define ZEIDX_U4  (NN * SLOTS / 8)
#define ZR_GRID   ((ZCNT_U4 + ZEIDX_U4 + 255) / 256)

typedef short bf16x8 __attribute__((ext_vector_type(8)));   // 8 bf16 = 4 VGPRs
typedef float f32x4  __attribute__((ext_vector_type(4)));

// ---- bf16 helpers (RNE) ----
__device__ __forceinline__ unsigned short f2bf(float f) {
    union { float f; unsigned u; } c; c.f = f;
    unsigned r = c.u + 0x7fffu + ((c.u >> 16) & 1u);
    return (unsigned short)(r >> 16);
}
__device__ __forceinline__ float bflo(unsigned p) { union { unsigned u; float f; } c; c.u = p << 16; return c.f; }
__device__ __forceinline__ float bfhi(unsigned p) { union { unsigned u; float f; } c; c.u = p & 0xffff0000u; return c.f; }
__device__ __forceinline__ unsigned packbf(float a, float b) { return (unsigned)f2bf(a) | ((unsigned)f2bf(b) << 16); }

// ---------------- cnt zero + eidx sentinel fill (must precede bucket atomics) ----------------
// eidx prefilled with NN (0xC350) so slots >= deg point at the zero sentinel row: the gather
// then needs NO cap-masking, every round index 0..15 is safe to load, and addresses don't
// depend on the deg load.
__global__ __launch_bounds__(256) void zero_kernel(int* __restrict__ cntpad, unsigned short* __restrict__ eidx) {
    int i = blockIdx.x * 256 + threadIdx.x;     // uint4 index
    if (i < ZCNT_U4) {
        ((uint4*)cntpad)[i] = make_uint4(0, 0, 0, 0);
    } else {
        int j = i - ZCNT_U4;
        if (j < ZEIDX_U4) ((uint4*)eidx)[j] = make_uint4(0xC350C350u, 0xC350C350u, 0xC350C350u, 0xC350C350u);
    }
}

// ---------------- merged prep + padded-slot CSR build (independent parts, one dispatch) ----
// R11 evidence: bucket (~40us) + prep (~25us) merged costs only ~45us (overlapped).
__global__ __launch_bounds__(256) void prepbucket_kernel(const int* __restrict__ src, const int* __restrict__ dst,
                                                         const float* __restrict__ x,
                                                         const float* __restrict__ W1l, const float* __restrict__ W1r,
                                                         const float* __restrict__ W2l, const float* __restrict__ W2r,
                                                         const float* __restrict__ W3l, const float* __restrict__ W3r,
                                                         int* __restrict__ cntpad, unsigned short* __restrict__ eidx,
                                                         unsigned short* __restrict__ xb,
                                                         unsigned short* __restrict__ Bw,
                                                         unsigned short* __restrict__ h1b,
                                                         unsigned short* __restrict__ h2b) {
    const int b = blockIdx.x;
    const int t = threadIdx.x;
    if (b < BKT_BLKS) {
        const int shard = b & (NSHARD - 1);
        const int chunk = b >> 3;
        const int lo = shard * SHARD_NODES;
        const int hi = lo + SHARD_NODES;
        int i = (chunk * 256 + t) * 4;
        if (i + 3 < EE) {
            int4 dv = *(const int4*)(dst + i);
            int4 sv = *(const int4*)(src + i);
            if (dv.x >= lo && dv.x < hi) { int p = atomicAdd(&cntpad[dv.x * CSTRIDE], 1); if (p < SLOTS) eidx[dv.x * SLOTS + p] = (unsigned short)sv.x; }
            if (dv.y >= lo && dv.y < hi) { int p = atomicAdd(&cntpad[dv.y * CSTRIDE], 1); if (p < SLOTS) eidx[dv.y * SLOTS + p] = (unsigned short)sv.y; }
            if (dv.z >= lo && dv.z < hi) { int p = atomicAdd(&cntpad[dv.z * CSTRIDE], 1); if (p < SLOTS) eidx[dv.z * SLOTS + p] = (unsigned short)sv.z; }
            if (dv.w >= lo && dv.w < hi) { int p = atomicAdd(&cntpad[dv.w * CSTRIDE], 1); if (p < SLOTS) eidx[dv.w * SLOTS + p] = (unsigned short)sv.w; }
        } else {
            for (int e = i; e < EE; ++e) {
                int d = dst[e];
                if (d >= lo && d < hi) {
                    int p = atomicAdd(&cntpad[d * CSTRIDE], 1);
                    if (p < SLOTS) eidx[d * SLOTS + p] = (unsigned short)src[e];
                }
            }
        }
    } else if (b < BKT_BLKS + CVT_BLKS) {
        int i = (b - BKT_BLKS) * 256 + t;         // float4 index, exactly NN*DD/4
        float4 v = ((const float4*)x)[i];
        uint2 o;
        o.x = packbf(v.x, v.y);
        o.y = packbf(v.z, v.w);
        ((uint2*)xb)[i] = o;
    } else if (b < BKT_BLKS + CVT_BLKS + WCAT_BLKS) {
        int gid = (b - BKT_BLKS - CVT_BLKS) * 256 + t;   // 0..98303
        int layer = gid >> 15;
        int rem = gid & 32767;
        int c = rem >> 8;
        int k = rem & 255;
        const float* Wl = (layer == 0) ? W1l : (layer == 1) ? W2l : W3l;
        const float* Wr = (layer == 0) ? W1r : (layer == 1) ? W2r : W3r;
        float v = (k < 128) ? Wl[(size_t)c * DD + k] : Wr[(size_t)c * DD + (k - 128)];
        Bw[gid] = f2bf(v);
    } else {
        // zero sentinel row NN of xb/h1b/h2b: 3 rows x 256B = 48 uint4
        if (t < 48) {
            unsigned short* base = (t < 16) ? xb : (t < 32) ? h1b : h2b;
            ((uint4*)(base + (size_t)NN * DD))[t & 15] = make_uint4(0, 0, 0, 0);
        }
    }
}

// ---------------- fused layer: gather 16 nodes -> LDS, then MFMA dual-GEMM ----------------
// R13 post-mortem: quarter-per-node pipeline via by-ref lambdas + conditional while-loop got
// DEMOTED TO SCRATCH (VGPR_Count stayed 32, WRITE_SIZE 27->114 MB = spill traffic) -> 87us.
// R14: same dataflow, demotion-proof shape: macro (no lambdas), single for-loop, UNCONDITIONAL
// prefetch of round (r+1)&15 (always safe: sentinel prefill makes all 16 rounds loadable;
// the last prefetch is discarded). Every variable assigned on every path -> clean SSA, stays
// in VGPRs. Payload 2x4 uint4 = 32 VGPR + 8 acc + temps ~= 55, fits (256,8)'s 64-VGPR cap.
// lane=(sub,q): quarter sub owns node, lane q privately accumulates channels 8q..8q+7 -> no
// cross-lane reduce. Per round the wave loads 16 rows (4/quarter), fully coalesced.
template <int RELU, int WRITE_F32>
__global__ __launch_bounds__(256, 8) void layer_kernel(const unsigned short* __restrict__ hb,
                                                       const unsigned short* __restrict__ eidx,
                                                       const int* __restrict__ cntpad,
                                                       const unsigned short* __restrict__ Bw,
                                                       const float* __restrict__ bias,
                                                       float* __restrict__ outf,
                                                       unsigned short* __restrict__ outb, int n) {
    (void)n;
    __shared__ __align__(16) unsigned short sA[16][136];
    const int tid  = threadIdx.x;
    const int w    = tid >> 6;          // wave 0..3
    const int lane = tid & 63;
    const int row0 = blockIdx.x * 16;
    const int sub  = lane >> 4;         // quarter 0..3 -> node within wave
    const int q    = lane & 15;         // 16B slot within the 256B row

    // ---- Phase A: 4 nodes per wave, one per quarter ----
    const int node = row0 + (w << 2) + sub;
    const int deg  = cntpad[node * CSTRIDE];
    // lane's 4 slot indices (slots q*4..q*4+3 of its node); sentinel-padded past deg
    uint2 mi = *(const uint2*)(eidx + (size_t)node * SLOTS + q * 4);

    const int cap = deg < SLOTS ? deg : SLOTS;
    int cmax = cap;
    cmax = max(cmax, __shfl_xor(cmax, 16));
    cmax = max(cmax, __shfl_xor(cmax, 32));
    const int rounds = (cmax + 3) >> 2;     // wave-uniform loop bound, 0..16

    float a0 = 0.f, a1 = 0.f, a2 = 0.f, a3 = 0.f, a4 = 0.f, a5 = 0.f, a6 = 0.f, a7 = 0.f;

// round RR (0..15): source lane (sub<<4)|RR holds slots 4*RR..4*RR+3 of this quarter's node
#define GLOAD(RR, V0, V1, V2, V3)                                             \
    {                                                                         \
        const int sl_ = (sub << 4) | (RR);                                    \
        unsigned p0_ = (unsigned)__shfl((int)mi.x, sl_);                      \
        unsigned p1_ = (unsigned)__shfl((int)mi.y, sl_);                      \
        V0 = ((const uint4*)(hb + (size_t)(p0_ & 0xffffu) * DD))[q];          \
        V1 = ((const uint4*)(hb + (size_t)(p0_ >> 16)     * DD))[q];          \
        V2 = ((const uint4*)(hb + (size_t)(p1_ & 0xffffu) * DD))[q];          \
        V3 = ((const uint4*)(hb + (size_t)(p1_ >> 16)     * DD))[q];          \
    }

    uint4 c0, c1, c2, c3, n0, n1, n2, n3;
    GLOAD(0, c0, c1, c2, c3);
    for (int r = 0; r < rounds; ++r) {
        GLOAD((r + 1) & 15, n0, n1, n2, n3);        // unconditional 1-ahead prefetch
        a0 += (bflo(c0.x) + bflo(c1.x)) + (bflo(c2.x) + bflo(c3.x));
        a1 += (bfhi(c0.x) + bfhi(c1.x)) + (bfhi(c2.x) + bfhi(c3.x));
        a2 += (bflo(c0.y) + bflo(c1.y)) + (bflo(c2.y) + bflo(c3.y));
        a3 += (bfhi(c0.y) + bfhi(c1.y)) + (bfhi(c2.y) + bfhi(c3.y));
        a4 += (bflo(c0.z) + bflo(c1.z)) + (bflo(c2.z) + bflo(c3.z));
        a5 += (bfhi(c0.z) + bfhi(c1.z)) + (bfhi(c2.z) + bfhi(c3.z));
        a6 += (bflo(c0.w) + bflo(c1.w)) + (bflo(c2.w) + bflo(c3.w));
        a7 += (bfhi(c0.w) + bfhi(c1.w)) + (bfhi(c2.w) + bfhi(c3.w));
        c0 = n0; c1 = n1; c2 = n2; c3 = n3;
    }
#undef GLOAD

    {
        const float inv = (deg > 0) ? (1.0f / (float)deg) : 0.f;
        uint4 o;
        o.x = packbf(a0 * inv, a1 * inv);
        o.y = packbf(a2 * inv, a3 * inv);
        o.z = packbf(a4 * inv, a5 * inv);
        o.w = packbf(a6 * inv, a7 * inv);
        *(uint4*)&sA[(w << 2) | sub][q * 8] = o;
    }
    __syncthreads();

    // ---- Phase B: MFMA dual-GEMM. All waves share the 16 rows; wave w owns 32 cols ----
    const int m    = lane & 15;
    const int quad = lane >> 4;
    const int arow = row0 + m;

    f32x4 acc[2];
    acc[0] = (f32x4){0.f, 0.f, 0.f, 0.f};
    acc[1] = (f32x4){0.f, 0.f, 0.f, 0.f};

    const unsigned short* aptr = hb + (size_t)arow * DD + quad * 8;
#pragma unroll
    for (int ph = 0; ph < 2; ++ph) {
#pragma unroll
        for (int ks = 0; ks < 4; ++ks) {
            bf16x8 af;
            if (ph == 0) {
                af = *(const bf16x8*)&sA[m][ks * 32 + quad * 8];
            } else {
                af = *(const bf16x8*)(aptr + ks * 32);
            }
            const int koff = ph * 128 + ks * 32 + quad * 8;
#pragma unroll
            for (int ct = 0; ct < 2; ++ct) {
                const int c = w * 32 + ct * 16 + m;
                bf16x8 bfv = *(const bf16x8*)(Bw + (size_t)c * 256 + koff);
                acc[ct] = __builtin_amdgcn_mfma_f32_16x16x32_bf16(af, bfv, acc[ct], 0, 0, 0);
            }
        }
    }

#pragma unroll
    for (int ct = 0; ct < 2; ++ct) {
        const int gcol = w * 32 + ct * 16 + m;
        const float bv = bias[gcol];
#pragma unroll
        for (int r = 0; r < 4; ++r) {
            const int grow = row0 + quad * 4 + r;
            float v = acc[ct][r] + bv;
            if (RELU) v = fmaxf(v, 0.f);
            if (WRITE_F32) outf[(size_t)grow * DD + gcol] = v;
            else           outb[(size_t)grow * DD + gcol] = f2bf(v);
        }
    }
}

extern "C" void kernel_launch(void* const* d_in, const int* in_sizes, int n_in,
                              void* d_out, int out_size, void* d_ws, size_t ws_size,
                              hipStream_t stream) {
    const float* x    = (const float*)d_in[0];
    const int*   edge = (const int*)d_in[1];     // [2, E] int32
    const int*   srcp = edge;
    const int*   dstp = edge + EE;
    const float* W1l = (const float*)d_in[2];
    const float* b1  = (const float*)d_in[3];
    const float* W1r = (const float*)d_in[4];
    const float* W2l = (const float*)d_in[5];
    const float* b2  = (const float*)d_in[6];
    const float* W2r = (const float*)d_in[7];
    const float* W3l = (const float*)d_in[8];
    const float* b3  = (const float*)d_in[9];
    const float* W3r = (const float*)d_in[10];
    float* out = (float*)d_out;

    char* ws = (char*)d_ws;
    size_t off = 0;
    auto alloc = [&](size_t bytes) { void* p = ws + off; off += (bytes + 255) & ~(size_t)255; return p; };
    unsigned short* eidx   = (unsigned short*)alloc((size_t)NN * SLOTS * 2);      // 6.4 MB padded slots
    int*            cntpad = (int*)           alloc((size_t)NN * CSTRIDE * 4);    // 3.2 MB line-strided counters
    unsigned short* Bw     = (unsigned short*)alloc((size_t)3 * DD * 256 * 2);
    unsigned short* xb     = (unsigned short*)alloc((size_t)(NN + 1) * DD * 2);   // +1 zero row (sentinel NN)
    unsigned short* h1b    = (unsigned short*)alloc((size_t)(NN + 1) * DD * 2);
    unsigned short* h2b    = (unsigned short*)alloc((size_t)(NN + 1) * DD * 2);

    zero_kernel<<<ZR_GRID, 256, 0, stream>>>(cntpad, eidx);

    const int pb_grid = BKT_BLKS + CVT_BLKS + WCAT_BLKS + ZR_BLKS;
    prepbucket_kernel<<<pb_grid, 256, 0, stream>>>(srcp, dstp, x, W1l, W1r, W2l, W2r, W3l, W3r,
                                                   cntpad, eidx, xb, Bw, h1b, h2b);

    const int layer_grid = (NN + 15) / 16;     // 3125

    // layer 1: xb -> h1b (ReLU)
    layer_kernel<1, 0><<<layer_grid, 256, 0, stream>>>(xb, eidx, cntpad, Bw, b1, nullptr, h1b, NN);
    // layer 2: h1b -> h2b (ReLU)
    layer_kernel<1, 0><<<layer_grid, 256, 0, stream>>>(h1b, eidx, cntpad, Bw + 32768, b2, nullptr, h2b, NN);
    // layer 3: h2b -> out fp32 (no ReLU)
    layer_kernel<0, 1><<<layer_grid, 256, 0, stream>>>(h2b, eidx, cntpad, Bw + 65536, b3, out, nullptr, NN);
}